// Round 1
// baseline (509.768 us; speedup 1.0000x reference)
//
#include <hip/hip_runtime.h>

#define F 128
#define NODES_PER_CHUNK 32
#define CHUNKS_PER_BLOCK 5   // 160 rows per block, 250 blocks covers 40000 rows

// ---------------------------------------------------------------------------
// Phase 1: q = x @ Wq, k = x @ Wk   (blockIdx.y = 0 -> q, 1 -> k)
// LDS: 64 KB for W + 16 KB x-tile = 80 KB -> 2 blocks/CU.
// Each thread owns a 4x4 register tile (rows 4*rg.., cols 4*cg..).
// ---------------------------------------------------------------------------
__global__ __launch_bounds__(256) void proj_kernel(
    const float* __restrict__ x,
    const float* __restrict__ Wq,
    const float* __restrict__ Wk,
    float* __restrict__ q,
    float* __restrict__ k)
{
    __shared__ float lds_w[F * F];                 // 64 KB
    __shared__ float lds_x[NODES_PER_CHUNK * F];   // 16 KB

    const int t   = threadIdx.x;
    const int isK = blockIdx.y;
    const float* __restrict__ W = isK ? Wk : Wq;
    float* __restrict__ outp    = isK ? k  : q;

    // stage W (16384 floats = 4096 float4) into LDS, coalesced
    {
        const float4* w4 = (const float4*)W;
        float4* l4 = (float4*)lds_w;
        #pragma unroll
        for (int i = 0; i < 16; ++i) l4[i * 256 + t] = w4[i * 256 + t];
    }

    const int cg = t & 31;   // column group: cols 4*cg .. 4*cg+3
    const int rg = t >> 5;   // row group (0..7): rows 4*rg .. 4*rg+3 within chunk

    for (int c = 0; c < CHUNKS_PER_BLOCK; ++c) {
        const int r0 = (blockIdx.x * CHUNKS_PER_BLOCK + c) * NODES_PER_CHUNK;

        __syncthreads();  // W staged (c==0) / previous chunk's x readers done
        {
            // stage x rows r0..r0+31 (4096 floats = 1024 float4), coalesced
            const float4* x4 = (const float4*)(x + (size_t)r0 * F);
            float4* l4 = (float4*)lds_x;
            #pragma unroll
            for (int i = 0; i < 4; ++i) l4[i * 256 + t] = x4[i * 256 + t];
        }
        __syncthreads();

        float acc[4][4] = {};
        #pragma unroll 4
        for (int f4 = 0; f4 < 32; ++f4) {
            float4 xv[4];
            #pragma unroll
            for (int r = 0; r < 4; ++r)
                xv[r] = *(const float4*)&lds_x[(4 * rg + r) * F + 4 * f4];
            #pragma unroll
            for (int j = 0; j < 4; ++j) {
                const float4 wv = *(const float4*)&lds_w[(4 * f4 + j) * F + 4 * cg];
                #pragma unroll
                for (int r = 0; r < 4; ++r) {
                    const float xs = ((const float*)&xv[r])[j];
                    acc[r][0] += xs * wv.x;
                    acc[r][1] += xs * wv.y;
                    acc[r][2] += xs * wv.z;
                    acc[r][3] += xs * wv.w;
                }
            }
        }

        #pragma unroll
        for (int r = 0; r < 4; ++r) {
            float4 v = make_float4(acc[r][0], acc[r][1], acc[r][2], acc[r][3]);
            *(float4*)&outp[(size_t)(r0 + 4 * rg + r) * F + 4 * cg] = v;
        }
    }
}

// ---------------------------------------------------------------------------
// Phase 2: out[p] = (1/sqrt(F)) * sum_f q[i,f] * w_ij[p,f] * k[j,f]
// One half-wave (32 lanes) per pair; each lane one float4 -> 512 B coalesced
// row reads; shfl_xor tree reduce within the half-wave.
// ---------------------------------------------------------------------------
__global__ __launch_bounds__(256) void edge_kernel(
    const float* __restrict__ w_ij,
    const int*   __restrict__ idx_i,
    const int*   __restrict__ idx_j,
    const float* __restrict__ q,
    const float* __restrict__ k,
    float* __restrict__ out)
{
    const int t = blockIdx.x * 256 + threadIdx.x;
    const int p = t >> 5;   // pair index
    const int l = t & 31;   // lane within half-wave

    const int i = idx_i[p];
    const int j = idx_j[p];

    const float4 wv = *(const float4*)&w_ij[(size_t)p * F + 4 * l];
    const float4 qv = *(const float4*)&q[(size_t)i * F + 4 * l];
    const float4 kv = *(const float4*)&k[(size_t)j * F + 4 * l];

    float s = qv.x * kv.x * wv.x
            + qv.y * kv.y * wv.y
            + qv.z * kv.z * wv.z
            + qv.w * kv.w * wv.w;

    s += __shfl_xor(s, 16);
    s += __shfl_xor(s, 8);
    s += __shfl_xor(s, 4);
    s += __shfl_xor(s, 2);
    s += __shfl_xor(s, 1);

    if (l == 0) out[p] = s * 0.088388347648318447f;  // 1/sqrt(128)
}

extern "C" void kernel_launch(void* const* d_in, const int* in_sizes, int n_in,
                              void* d_out, int out_size, void* d_ws, size_t ws_size,
                              hipStream_t stream) {
    const float* x     = (const float*)d_in[0];
    const float* w_ij  = (const float*)d_in[1];
    const int*   idx_i = (const int*)d_in[2];
    const int*   idx_j = (const int*)d_in[3];
    const float* Wq    = (const float*)d_in[4];
    const float* Wk    = (const float*)d_in[5];
    float* out = (float*)d_out;

    const int n_nodes = in_sizes[0] / F;   // 40000
    const int n_pairs = in_sizes[2];       // 640000

    float* q = (float*)d_ws;
    float* k = q + (size_t)n_nodes * F;

    // Phase 1: 250 x-blocks * (q,k), 160 rows each
    dim3 g1(n_nodes / (NODES_PER_CHUNK * CHUNKS_PER_BLOCK), 2);
    proj_kernel<<<g1, 256, 0, stream>>>(x, Wq, Wk, q, k);

    // Phase 2: 8 pairs per 256-thread block
    int g2 = (n_pairs * 32) / 256;
    edge_kernel<<<g2, 256, 0, stream>>>(w_ij, idx_i, idx_j, q, k, out);
}

// Round 2
// 486.435 us; speedup vs baseline: 1.0480x; 1.0480x over previous
//
#include <hip/hip_runtime.h>

#define F 128
#define NODES_PER_CHUNK 32
#define CHUNKS_PER_BLOCK 5   // 160 rows per block, 250 blocks covers 40000 rows

// fp32 -> bf16 round-to-nearest-even (inputs are normal floats here)
static __device__ __forceinline__ unsigned short f2bf(float f) {
    unsigned int u = __float_as_uint(f);
    u += 0x7FFFu + ((u >> 16) & 1u);
    return (unsigned short)(u >> 16);
}
static __device__ __forceinline__ float bf2f(unsigned short h) {
    return __uint_as_float(((unsigned int)h) << 16);
}

// ---------------------------------------------------------------------------
// Phase 1: q = x @ Wq, k = x @ Wk   (blockIdx.y = 0 -> q, 1 -> k)
// fp32 compute (exact), bf16 store. LDS: 64 KB W + 16 KB x-tile -> 2 blk/CU.
// ---------------------------------------------------------------------------
__global__ __launch_bounds__(256) void proj_kernel(
    const float* __restrict__ x,
    const float* __restrict__ Wq,
    const float* __restrict__ Wk,
    unsigned short* __restrict__ q,   // bf16 bits
    unsigned short* __restrict__ k)
{
    __shared__ float lds_w[F * F];                 // 64 KB
    __shared__ float lds_x[NODES_PER_CHUNK * F];   // 16 KB

    const int t   = threadIdx.x;
    const int isK = blockIdx.y;
    const float* __restrict__ W      = isK ? Wk : Wq;
    unsigned short* __restrict__ outp = isK ? k  : q;

    // stage W (16384 floats = 4096 float4) into LDS, coalesced
    {
        const float4* w4 = (const float4*)W;
        float4* l4 = (float4*)lds_w;
        #pragma unroll
        for (int i = 0; i < 16; ++i) l4[i * 256 + t] = w4[i * 256 + t];
    }

    const int cg = t & 31;   // column group: cols 4*cg .. 4*cg+3
    const int rg = t >> 5;   // row group (0..7): rows 4*rg .. 4*rg+3 within chunk

    for (int c = 0; c < CHUNKS_PER_BLOCK; ++c) {
        const int r0 = (blockIdx.x * CHUNKS_PER_BLOCK + c) * NODES_PER_CHUNK;

        __syncthreads();  // W staged (c==0) / previous chunk's x readers done
        {
            const float4* x4 = (const float4*)(x + (size_t)r0 * F);
            float4* l4 = (float4*)lds_x;
            #pragma unroll
            for (int i = 0; i < 4; ++i) l4[i * 256 + t] = x4[i * 256 + t];
        }
        __syncthreads();

        float acc[4][4] = {};
        #pragma unroll 4
        for (int f4 = 0; f4 < 32; ++f4) {
            float4 xv[4];
            #pragma unroll
            for (int r = 0; r < 4; ++r)
                xv[r] = *(const float4*)&lds_x[(4 * rg + r) * F + 4 * f4];
            #pragma unroll
            for (int j = 0; j < 4; ++j) {
                const float4 wv = *(const float4*)&lds_w[(4 * f4 + j) * F + 4 * cg];
                #pragma unroll
                for (int r = 0; r < 4; ++r) {
                    const float xs = ((const float*)&xv[r])[j];
                    acc[r][0] += xs * wv.x;
                    acc[r][1] += xs * wv.y;
                    acc[r][2] += xs * wv.z;
                    acc[r][3] += xs * wv.w;
                }
            }
        }

        #pragma unroll
        for (int r = 0; r < 4; ++r) {
            ushort4 v;
            v.x = f2bf(acc[r][0]);
            v.y = f2bf(acc[r][1]);
            v.z = f2bf(acc[r][2]);
            v.w = f2bf(acc[r][3]);
            *(ushort4*)&outp[(size_t)(r0 + 4 * rg + r) * F + 4 * cg] = v;
        }
    }
}

// ---------------------------------------------------------------------------
// Phase 2: out[p] = (1/sqrt(F)) * sum_f q[i,f] * w_ij[p,f] * k[j,f]
// 32 lanes per pair: w_ij float4 (16 B/lane), q/k bf16 ushort4 (8 B/lane).
// Gather traffic halved vs fp32 q/k.
// ---------------------------------------------------------------------------
__global__ __launch_bounds__(256) void edge_kernel(
    const float* __restrict__ w_ij,
    const int*   __restrict__ idx_i,
    const int*   __restrict__ idx_j,
    const unsigned short* __restrict__ q,
    const unsigned short* __restrict__ k,
    float* __restrict__ out)
{
    const int t = blockIdx.x * 256 + threadIdx.x;
    const int p = t >> 5;   // pair index
    const int l = t & 31;   // lane within half-wave

    const int i = idx_i[p];
    const int j = idx_j[p];

    const float4  wv = *(const float4*)&w_ij[(size_t)p * F + 4 * l];
    const ushort4 qv = *(const ushort4*)&q[(size_t)i * F + 4 * l];
    const ushort4 kv = *(const ushort4*)&k[(size_t)j * F + 4 * l];

    float s = bf2f(qv.x) * bf2f(kv.x) * wv.x
            + bf2f(qv.y) * bf2f(kv.y) * wv.y
            + bf2f(qv.z) * bf2f(kv.z) * wv.z
            + bf2f(qv.w) * bf2f(kv.w) * wv.w;

    s += __shfl_xor(s, 16);
    s += __shfl_xor(s, 8);
    s += __shfl_xor(s, 4);
    s += __shfl_xor(s, 2);
    s += __shfl_xor(s, 1);

    if (l == 0) out[p] = s * 0.088388347648318447f;  // 1/sqrt(128)
}

extern "C" void kernel_launch(void* const* d_in, const int* in_sizes, int n_in,
                              void* d_out, int out_size, void* d_ws, size_t ws_size,
                              hipStream_t stream) {
    const float* x     = (const float*)d_in[0];
    const float* w_ij  = (const float*)d_in[1];
    const int*   idx_i = (const int*)d_in[2];
    const int*   idx_j = (const int*)d_in[3];
    const float* Wq    = (const float*)d_in[4];
    const float* Wk    = (const float*)d_in[5];
    float* out = (float*)d_out;

    const int n_nodes = in_sizes[0] / F;   // 40000
    const int n_pairs = in_sizes[2];       // 640000

    unsigned short* q = (unsigned short*)d_ws;
    unsigned short* k = q + (size_t)n_nodes * F;

    dim3 g1(n_nodes / (NODES_PER_CHUNK * CHUNKS_PER_BLOCK), 2);
    proj_kernel<<<g1, 256, 0, stream>>>(x, Wq, Wk, q, k);

    int g2 = (n_pairs * 32) / 256;
    edge_kernel<<<g2, 256, 0, stream>>>(w_ij, idx_i, idx_j, q, k, out);
}